// Round 16
// baseline (3569.418 us; speedup 1.0000x reference)
//
#include <hip/hip_runtime.h>
#include <hip/hip_fp16.h>
#include <cstdint>

// LSTMNet: embed(128->512) -> 3x LSTM(512) -> decode last step.
// B=256, T=256. f16 MFMA (16x16x32), fp32 accum, fp32 cell state.
//
// R16 = R15-fallback (== R11 + single-phase reduce; best: 2944us) with the
// per-hb flag array replaced by AGGREGATED MONOTONE COUNTERS:
//   count[l][g] += 1 (agent fetch_add, 1 thread) after each layer-l publish
//   poll: 3 threads/block wait count[l][g] >= 32*min(r-l,TT)
// Rationale: R15's 96 polling threads x 256 blocks hammered 3 cache lines
// at MALL every ~0.4us (~25k concurrent same-line requests) - a bank
// hotspot that queues every round and delays the h-loads the flags gate.
// Counters cut poll traffic 32x. Semantics identical (count==32*need <=>
// all 32 peers done; monotone, no wrap, no reset).
// Everything else identical to R15's executed path: 256 blocks coop,
// g=blockIdx&7 (32 batch rows, all on XCD g by round-robin), hb=blockIdx>>3
// (16 hidden units); W0,W1 VGPR frags, W2 128KB LDS, Pl 32KB single-phase;
// depth-16 h rings, agent-scope h loads/stores (ld_cg16/st_cg2, spill-safe);
// one drain + publishes at round end; guarded spins; rule #20 respected.

#define TT   256
#define NBAT 256
#define DIN  128
#define HID  512
#define RD   16

typedef _Float16 half_t;
typedef __attribute__((ext_vector_type(8))) _Float16 half8;
typedef __attribute__((ext_vector_type(4))) _Float16 half4v;
typedef __attribute__((ext_vector_type(4))) float f32x4;

__device__ __forceinline__ float sigmoidf_(float x) {
    return 1.f / (1.f + __expf(-x));
}
__device__ __forceinline__ float tanhf_(float x) {
    float xc = fminf(fmaxf(x, -15.f), 15.f);
    float e = __expf(2.f * xc);
    return (e - 1.f) / (e + 1.f);
}

// agent-scope (IF-coherent) 16B load; compiler-managed waits => spill-safe
__device__ __forceinline__ half8 ld_cg16(const half_t* p) {
    union { unsigned long long u[2]; half8 v; } r;
    r.u[0] = __hip_atomic_load((const unsigned long long*)p,
                               __ATOMIC_RELAXED, __HIP_MEMORY_SCOPE_AGENT);
    r.u[1] = __hip_atomic_load((const unsigned long long*)p + 1,
                               __ATOMIC_RELAXED, __HIP_MEMORY_SCOPE_AGENT);
    return r.v;
}
// agent-scope 2B store of one h value
__device__ __forceinline__ void st_cg2(half_t* p, float v) {
    half_t h = (half_t)v;
    unsigned short b = __builtin_bit_cast(unsigned short, h);
    __hip_atomic_store((unsigned short*)p, b,
                       __ATOMIC_RELAXED, __HIP_MEMORY_SCOPE_AGENT);
}

// write BOTH m-phases of partials into Pl[128][64] (XOR swizzle, 2-way free)
__device__ __forceinline__ void phase_out2(float* Pl, const f32x4 acc[2][4],
                                           int wv, int lane) {
    #pragma unroll
    for (int m = 0; m < 2; ++m)
        #pragma unroll
        for (int n = 0; n < 4; ++n)
            #pragma unroll
            for (int q = 0; q < 4; ++q) {
                int prow = (wv << 5) + (m << 4) + ((lane >> 4) << 2) + q;
                int cidx = (n << 4) + (lane & 15);
                Pl[prow * 64 + (cidx ^ ((((prow >> 2) ^ prow) & 1) << 4))] = acc[m][n][q];
            }
}
// reduce 4 K-chunk partials for batch-row `brow` + bias -> gates -> h
__device__ __forceinline__ float red_gatesS(const float* Pl, const float* b4,
                                            int brow, int jj, float& c) {
    float gs[4];
    #pragma unroll
    for (int gt = 0; gt < 4; ++gt) {
        float s = b4[gt];
        int cidx = (gt << 4) + jj;
        #pragma unroll
        for (int w2 = 0; w2 < 4; ++w2) {
            int r0 = (w2 << 5) + brow;
            s += Pl[r0 * 64 + (cidx ^ ((((r0 >> 2) ^ r0) & 1) << 4))];
        }
        gs[gt] = s;
    }
    float ig = sigmoidf_(gs[0]), fg = sigmoidf_(gs[1]);
    float gg = tanhf_(gs[2]), og = sigmoidf_(gs[3]);
    c = fg * c + ig * gg;
    return og * tanhf_(c);
}

// ---------------- weight conversion: fp32 w_ih|w_hh -> f16 MFMA-frag order
__global__ __launch_bounds__(256) void k_w16(const float* __restrict__ wih,
                                             const float* __restrict__ whh,
                                             half_t* __restrict__ wbuf) {
    half8* wb = (half8*)wbuf;
    const int bid = blockIdx.x;                // 0..383
    const int l = bid >> 7;
    const int rem = bid & 127;
    const int hb = rem >> 2, q = rem & 3;
    const int tid = threadIdx.x;
    #pragma unroll
    for (int i = 0; i < 8; ++i) {
        int unit = tid + (i << 8);             // 0..2047
        int kit = unit >> 8, n = (unit >> 6) & 3, lane = unit & 63;
        int grow = l * 2048 + n * 512 + hb * 16 + (lane & 15);
        int col = q * 256 + kit * 32 + ((lane >> 4) << 3);
        const float* src = (col < 512) ? (wih + (size_t)grow * HID + col)
                                       : (whh + (size_t)grow * HID + (col - 512));
        float4 u0 = *(const float4*)src;
        float4 u1 = *(const float4*)(src + 4);
        wb[((size_t)(l * 32 + hb) * 4 + q) * 2048 + unit] =
            (half8){(half_t)u0.x, (half_t)u0.y, (half_t)u0.z, (half_t)u0.w,
                    (half_t)u1.x, (half_t)u1.y, (half_t)u1.z, (half_t)u1.w};
    }
}

// ---------------- embed: out[t][b][j] = f16( x[b][t][:] . W[j][:] + bias[j] )
__global__ __launch_bounds__(256) void k_embed(const float* __restrict__ x,
                                               const float* __restrict__ W,
                                               const float* __restrict__ bias,
                                               half_t* __restrict__ out) {
    extern __shared__ char smem[];
    half_t* Xs = (half_t*)smem;            // [64][128] swizzled
    half_t* Ws = (half_t*)(smem + 16384);  // [512][128] swizzled
    const int tid = threadIdx.x;
    const int bk = blockIdx.x;
    const int t = bk >> 2, b0 = (bk & 3) << 6;

    #pragma unroll
    for (int it = 0; it < 8; ++it) {
        int idx = tid + (it << 8);
        int r = idx >> 5, k = (idx & 31) << 2;
        float4 v = *(const float4*)(x + ((size_t)(b0 + r) * TT + t) * DIN + k);
        half4v hv = {(half_t)v.x, (half_t)v.y, (half_t)v.z, (half_t)v.w};
        int byte = r * 256 + ((k * 2) ^ ((r & 7) << 4));
        *(half4v*)((char*)Xs + byte) = hv;
    }
    #pragma unroll 4
    for (int it = 0; it < 64; ++it) {
        int idx = tid + (it << 8);
        int r = idx >> 5, k = (idx & 31) << 2;
        float4 v = *(const float4*)(W + (size_t)r * DIN + k);
        half4v hv = {(half_t)v.x, (half_t)v.y, (half_t)v.z, (half_t)v.w};
        int byte = r * 256 + ((k * 2) ^ ((r & 7) << 4));
        *(half4v*)((char*)Ws + byte) = hv;
    }
    __syncthreads();

    const int lane = tid & 63, wv = tid >> 6;
    f32x4 acc[4][8];
    #pragma unroll
    for (int m = 0; m < 4; ++m)
        #pragma unroll
        for (int n = 0; n < 8; ++n) acc[m][n] = (f32x4){0.f, 0.f, 0.f, 0.f};

    #pragma unroll
    for (int kit = 0; kit < 4; ++kit) {
        int kk = (kit << 5) + ((lane >> 4) << 3);
        half8 a[4];
        #pragma unroll
        for (int m = 0; m < 4; ++m) {
            int r = (m << 4) + (lane & 15);
            int byte = r * 256 + ((kk * 2) ^ ((r & 7) << 4));
            a[m] = *(half8*)((char*)Xs + byte);
        }
        #pragma unroll
        for (int n = 0; n < 8; ++n) {
            int r = (wv << 7) + (n << 4) + (lane & 15);
            int byte = r * 256 + ((kk * 2) ^ ((r & 7) << 4));
            half8 b = *(half8*)((char*)Ws + byte);
            #pragma unroll
            for (int m = 0; m < 4; ++m)
                acc[m][n] = __builtin_amdgcn_mfma_f32_16x16x32_f16(a[m], b, acc[m][n], 0, 0, 0);
        }
    }
    __syncthreads();
    half_t* Os = (half_t*)smem;
    #pragma unroll
    for (int n = 0; n < 8; ++n) {
        int j = (wv << 7) + (n << 4) + (lane & 15);
        float bj = bias[j];
        #pragma unroll
        for (int m = 0; m < 4; ++m)
            #pragma unroll
            for (int r = 0; r < 4; ++r) {
                int mr = (m << 4) + ((lane >> 4) << 2) + r;
                Os[mr * 512 + j] = (half_t)(acc[m][n][r] + bj);
            }
    }
    __syncthreads();
    #pragma unroll
    for (int it = 0; it < 16; ++it) {
        int idx = tid + (it << 8);
        int r = idx >> 6, c = (idx & 63) << 3;
        half8 v = *(half8*)(Os + r * 512 + c);
        *(half8*)(out + ((size_t)t * NBAT + (b0 + r)) * HID + c) = v;
    }
}

// ---------------- persistent pipelined recurrent kernel
__global__ __launch_bounds__(256, 1) void k_rec(const half_t* __restrict__ wbuf,
                                                const half_t* __restrict__ bufE,
                                                half_t* __restrict__ ring0,
                                                half_t* __restrict__ ring1,
                                                half_t* __restrict__ ring2,
                                                half_t* __restrict__ outbuf,
                                                const float* __restrict__ b_ih,
                                                const float* __restrict__ b_hh,
                                                int* __restrict__ counts) {
    extern __shared__ char smem[];
    half8* W2s = (half8*)smem;                 // [4 q][8 kit][4 n][64] = 128KB
    float* Pl = (float*)(smem + 131072);       // [128][64] f32 = 32KB single-phase

    const half8* wb = (const half8*)wbuf;
    const int tid = threadIdx.x;
    const int lane = tid & 63, wv = tid >> 6;
    const int g = blockIdx.x & 7;
    const int hb = blockIdx.x >> 3;
    const int b0 = g << 5;
    const int j0 = hb << 4;
    const int rr = tid >> 4;                   // reduce row 0..15
    const int jj = tid & 15;
    const bool low = (wv < 2);                 // waves 0,1: E+h1; waves 2,3: h0+h2
    const int qw = wv ^ 2;                     // L1 K-quarter for this wave
    const int koff = ((wv & 1) << 8) + ((lane >> 4) << 3);
    bool dead = false;

    // ---- startup: W0,W1 -> VGPR; W2 -> LDS; biases
    half8 Bf0[8][4], Bf1[8][4];
    {
        const half8* w0 = wb + ((size_t)hb * 4 + wv) * 2048;
        const half8* w1 = wb + ((size_t)(32 + hb) * 4 + qw) * 2048;
        #pragma unroll
        for (int kit = 0; kit < 8; ++kit)
            #pragma unroll
            for (int n = 0; n < 4; ++n) {
                Bf0[kit][n] = w0[kit * 256 + n * 64 + lane];
                Bf1[kit][n] = w1[kit * 256 + n * 64 + lane];
            }
    }
    {
        const half8* w2 = wb + (size_t)(64 + hb) * 4 * 2048;
        #pragma unroll 4
        for (int it = 0; it < 32; ++it) {
            int idx = tid + (it << 8);
            W2s[idx] = w2[idx];
        }
    }
    float bias[3][4];
    #pragma unroll
    for (int l = 0; l < 3; ++l)
        #pragma unroll
        for (int gt = 0; gt < 4; ++gt)
            bias[l][gt] = b_ih[(size_t)l * 2048 + gt * HID + j0 + jj] +
                          b_hh[(size_t)l * 2048 + gt * HID + j0 + jj];
    float cA0 = 0.f, cA1 = 0.f, cB0 = 0.f, cB1 = 0.f, cC0 = 0.f, cC1 = 0.f;
    __syncthreads();

    const size_t RNG = (size_t)NBAT * HID;

    for (int r = 0; r < TT + 2; ++r) {
        const bool act0 = (r < TT);
        const bool act1 = (r >= 1 && r <= TT);
        const bool act2 = (r >= 2);

        // ---- top poll: 3 threads, count[l][g] >= 32*min(r-l, TT)
        if (tid < 3 && !dead) {
            int l = tid;
            int need = r - l; if (need > TT) need = TT;
            if (need > 0) {
                const int* cp = counts + l * 8 + g;
                const int want = need << 5;    // 32 * need
                int guard = 0;
                while (__hip_atomic_load(cp, __ATOMIC_RELAXED,
                                         __HIP_MEMORY_SCOPE_AGENT) < want) {
                    __builtin_amdgcn_s_sleep(1);
                    if (++guard > (1 << 17)) { dead = true; break; }
                }
            }
        }
        __syncthreads();

        // ---- p0: low = E(r) (plain cached), high = h0(r-1) (agent)
        half8 p0a[8], p0b[8];
        const size_t rowb = (size_t)(b0 + (lane & 15)) * HID + koff;
        if (low) {
            if (act0) {
                const half_t* ar = bufE + (size_t)r * RNG + rowb;
                #pragma unroll
                for (int kit = 0; kit < 8; ++kit) {
                    p0a[kit] = *(const half8*)(ar + (kit << 5));
                    p0b[kit] = *(const half8*)(ar + (size_t)16 * HID + (kit << 5));
                }
            }
        } else if (act1) {
            const half_t* ar = ring0 + (size_t)((r - 1) & (RD - 1)) * RNG + rowb;
            #pragma unroll
            for (int kit = 0; kit < 8; ++kit) {
                p0a[kit] = ld_cg16(ar + (kit << 5));
                p0b[kit] = ld_cg16(ar + (size_t)16 * HID + (kit << 5));
            }
        }

        f32x4 acc[2][4];

        // ================= layer 0 (step r): A = p0, B = Bf0 (VGPR) ==========
        #pragma unroll
        for (int m = 0; m < 2; ++m)
            #pragma unroll
            for (int n = 0; n < 4; ++n) acc[m][n] = (f32x4){0.f, 0.f, 0.f, 0.f};
        if (act0 && (low || r >= 1)) {
            #pragma unroll
            for (int kit = 0; kit < 8; ++kit)
                #pragma unroll
                for (int n = 0; n < 4; ++n) {
                    acc[0][n] = __builtin_amdgcn_mfma_f32_16x16x32_f16(p0a[kit], Bf0[kit][n], acc[0][n], 0, 0, 0);
                    acc[1][n] = __builtin_amdgcn_mfma_f32_16x16x32_f16(p0b[kit], Bf0[kit][n], acc[1][n], 0, 0, 0);
                }
        }
        // low: issue h1(r-2) now; hides under L0 reduce
        half8 p1a[8], p1b[8];
        if (low && r >= 2) {
            const half_t* ar = ring1 + (size_t)((r - 2) & (RD - 1)) * RNG + rowb;
            #pragma unroll
            for (int kit = 0; kit < 8; ++kit) {
                p1a[kit] = ld_cg16(ar + (kit << 5));
                p1b[kit] = ld_cg16(ar + (size_t)16 * HID + (kit << 5));
            }
        }
        {   // L0 single-phase reduce/gates/store -> ring0 slot r
            half_t* dst = ring0 + (size_t)(r & (RD - 1)) * RNG;
            phase_out2(Pl, acc, wv, lane);     // top-poll barrier protects Pl
            __syncthreads();
            if (act0) {
                st_cg2(dst + (size_t)(b0 + rr) * HID + j0 + jj,
                       red_gatesS(Pl, bias[0], rr, jj, cA0));
                st_cg2(dst + (size_t)(b0 + 16 + rr) * HID + j0 + jj,
                       red_gatesS(Pl, bias[0], 16 + rr, jj, cA1));
            }
            __syncthreads();
        }

        // ================= layer 1 (step r-1): low A=p1(h1), high A=p0(h0) ===
        #pragma unroll
        for (int m = 0; m < 2; ++m)
            #pragma unroll
            for (int n = 0; n < 4; ++n) acc[m][n] = (f32x4){0.f, 0.f, 0.f, 0.f};
        if (act1) {
            if (!low) {
                #pragma unroll
                for (int kit = 0; kit < 8; ++kit)
                    #pragma unroll
                    for (int n = 0; n < 4; ++n) {
                        acc[0][n] = __builtin_amdgcn_mfma_f32_16x16x32_f16(p0a[kit], Bf1[kit][n], acc[0][n], 0, 0, 0);
                        acc[1][n] = __builtin_amdgcn_mfma_f32_16x16x32_f16(p0b[kit], Bf1[kit][n], acc[1][n], 0, 0, 0);
                    }
            } else if (r >= 2) {
                #pragma unroll
                for (int kit = 0; kit < 8; ++kit)
                    #pragma unroll
                    for (int n = 0; n < 4; ++n) {
                        acc[0][n] = __builtin_amdgcn_mfma_f32_16x16x32_f16(p1a[kit], Bf1[kit][n], acc[0][n], 0, 0, 0);
                        acc[1][n] = __builtin_amdgcn_mfma_f32_16x16x32_f16(p1b[kit], Bf1[kit][n], acc[1][n], 0, 0, 0);
                    }
            }
        }
        // high: issue h2(r-3) now; hides under L1 reduce
        if (!low && r >= 3) {
            const half_t* ar = ring2 + (size_t)((r - 3) & (RD - 1)) * RNG + rowb;
            #pragma unroll
            for (int kit = 0; kit < 8; ++kit) {
                p1a[kit] = ld_cg16(ar + (kit << 5));
                p1b[kit] = ld_cg16(ar + (size_t)16 * HID + (kit << 5));
            }
        }
        {   // L1 single-phase -> ring1 slot r-1
            half_t* dst = ring1 + (size_t)((r - 1) & (RD - 1)) * RNG;
            phase_out2(Pl, acc, wv, lane);
            __syncthreads();
            if (act1) {
                st_cg2(dst + (size_t)(b0 + rr) * HID + j0 + jj,
                       red_gatesS(Pl, bias[1], rr, jj, cB0));
                st_cg2(dst + (size_t)(b0 + 16 + rr) * HID + j0 + jj,
                       red_gatesS(Pl, bias[1], 16 + rr, jj, cB1));
            }
            __syncthreads();
        }

        // ================= layer 2 (step r-2): A = p1, B = W2s (LDS) =========
        #pragma unroll
        for (int m = 0; m < 2; ++m)
            #pragma unroll
            for (int n = 0; n < 4; ++n) acc[m][n] = (f32x4){0.f, 0.f, 0.f, 0.f};
        if (act2 && (low || r >= 3)) {
            const half8* w2l = W2s + ((size_t)wv << 11);
            #pragma unroll
            for (int kit = 0; kit < 8; ++kit) {
                half8 B0 = w2l[kit * 256 + 0 * 64 + lane];
                half8 B1 = w2l[kit * 256 + 1 * 64 + lane];
                half8 B2 = w2l[kit * 256 + 2 * 64 + lane];
                half8 B3 = w2l[kit * 256 + 3 * 64 + lane];
                acc[0][0] = __builtin_amdgcn_mfma_f32_16x16x32_f16(p1a[kit], B0, acc[0][0], 0, 0, 0);
                acc[1][0] = __builtin_amdgcn_mfma_f32_16x16x32_f16(p1b[kit], B0, acc[1][0], 0, 0, 0);
                acc[0][1] = __builtin_amdgcn_mfma_f32_16x16x32_f16(p1a[kit], B1, acc[0][1], 0, 0, 0);
                acc[1][1] = __builtin_amdgcn_mfma_f32_16x16x32_f16(p1b[kit], B1, acc[1][1], 0, 0, 0);
                acc[0][2] = __builtin_amdgcn_mfma_f32_16x16x32_f16(p1a[kit], B2, acc[0][2], 0, 0, 0);
                acc[1][2] = __builtin_amdgcn_mfma_f32_16x16x32_f16(p1b[kit], B2, acc[1][2], 0, 0, 0);
                acc[0][3] = __builtin_amdgcn_mfma_f32_16x16x32_f16(p1a[kit], B3, acc[0][3], 0, 0, 0);
                acc[1][3] = __builtin_amdgcn_mfma_f32_16x16x32_f16(p1b[kit], B3, acc[1][3], 0, 0, 0);
            }
        }
        {   // L2 single-phase -> ring2 slot r-2 (+ outbuf at final step)
            const int t2 = r - 2;
            half_t* dst = ring2 + (size_t)(t2 & (RD - 1)) * RNG;
            phase_out2(Pl, acc, wv, lane);
            __syncthreads();
            if (act2) {
                float h0v = red_gatesS(Pl, bias[2], rr, jj, cC0);
                float h1v = red_gatesS(Pl, bias[2], 16 + rr, jj, cC1);
                st_cg2(dst + (size_t)(b0 + rr) * HID + j0 + jj, h0v);
                st_cg2(dst + (size_t)(b0 + 16 + rr) * HID + j0 + jj, h1v);
                if (t2 == TT - 1) {
                    st_cg2(outbuf + (size_t)(b0 + rr) * HID + j0 + jj, h0v);
                    st_cg2(outbuf + (size_t)(b0 + 16 + rr) * HID + j0 + jj, h1v);
                }
            }
        }

        // ---- release: one drain, barrier, 3 counter increments
        asm volatile("s_waitcnt vmcnt(0)" ::: "memory");
        __builtin_amdgcn_sched_barrier(0);
        __syncthreads();
        if (tid == 0 && act0)
            __hip_atomic_fetch_add(counts + 0 * 8 + g, 1,
                                   __ATOMIC_RELAXED, __HIP_MEMORY_SCOPE_AGENT);
        if (tid == 1 && act1)
            __hip_atomic_fetch_add(counts + 1 * 8 + g, 1,
                                   __ATOMIC_RELAXED, __HIP_MEMORY_SCOPE_AGENT);
        if (tid == 2 && act2)
            __hip_atomic_fetch_add(counts + 2 * 8 + g, 1,
                                   __ATOMIC_RELAXED, __HIP_MEMORY_SCOPE_AGENT);
    }
}

// ---------------- decoder: out[b] = h2[T-1][b][:] . dec_W + dec_b
__global__ __launch_bounds__(256) void k_dec(const half_t* __restrict__ act,
                                             const float* __restrict__ dW,
                                             const float* __restrict__ db,
                                             float* __restrict__ out) {
    int tid = threadIdx.x;
    int bl = tid >> 3, part = tid & 7;
    int b = (blockIdx.x << 5) + bl;
    const half_t* row = act + (size_t)b * HID + (part << 6);
    float s = 0.f;
    #pragma unroll
    for (int i = 0; i < 8; ++i) {
        half8 v = ld_cg16(row + (i << 3));
        const float* wp = dW + (part << 6) + (i << 3);
        #pragma unroll
        for (int u = 0; u < 8; ++u) s += (float)v[u] * wp[u];
    }
    #pragma unroll
    for (int off = 1; off < 8; off <<= 1) s += __shfl_xor(s, off, 64);
    if (part == 0) out[b] = s + db[0];
}

extern "C" void kernel_launch(void* const* d_in, const int* in_sizes, int n_in,
                              void* d_out, int out_size, void* d_ws, size_t ws_size,
                              hipStream_t stream) {
    const float* x = (const float*)d_in[0];
    const float* eW = (const float*)d_in[1];
    const float* eb = (const float*)d_in[2];
    const float* wih = (const float*)d_in[3];
    const float* whh = (const float*)d_in[4];
    const float* bih = (const float*)d_in[5];
    const float* bhh = (const float*)d_in[6];
    const float* dW = (const float*)d_in[7];
    const float* db = (const float*)d_in[8];
    float* out = (float*)d_out;

    const size_t MB = 1u << 20;
    if (ws_size < 96 * MB + 65536) return;        // insufficient workspace

    char* ws = (char*)d_ws;
    half_t* bufE = (half_t*)ws;                   // 64 MB
    half_t* ring0 = (half_t*)(ws + 64 * MB);      // 4 MB each (depth 16)
    half_t* ring1 = (half_t*)(ws + 68 * MB);
    half_t* ring2 = (half_t*)(ws + 72 * MB);
    half_t* outbuf = (half_t*)(ws + 76 * MB);
    half_t* wbuf = (half_t*)(ws + 80 * MB);
    int* counts = (int*)(ws + 96 * MB);           // 24 monotone counters

    hipMemsetAsync(counts, 0, 1024 * sizeof(int), stream);

    (void)hipFuncSetAttribute((const void*)k_embed,
                              hipFuncAttributeMaxDynamicSharedMemorySize, 147456);
    (void)hipFuncSetAttribute((const void*)k_rec,
                              hipFuncAttributeMaxDynamicSharedMemorySize, 163840);

    k_w16<<<384, 256, 0, stream>>>(wih, whh, wbuf);
    k_embed<<<1024, 256, 147456, stream>>>(x, eW, eb, bufE);

    void* args[] = { (void*)&wbuf, (void*)&bufE, (void*)&ring0, (void*)&ring1,
                     (void*)&ring2, (void*)&outbuf, (void*)&bih, (void*)&bhh,
                     (void*)&counts };
    hipError_t ce = hipLaunchCooperativeKernel((const void*)k_rec, dim3(256), dim3(256),
                                               args, 163840, stream);
    if (ce != hipSuccess) {
        k_rec<<<256, 256, 163840, stream>>>(wbuf, bufE, ring0, ring1, ring2,
                                            outbuf, bih, bhh, counts);
    }

    k_dec<<<8, 256, 0, stream>>>(outbuf, dW, db, out);
}

// Round 19
// 2877.079 us; speedup vs baseline: 1.2406x; 1.2406x over previous
//
#include <hip/hip_runtime.h>
#include <hip/hip_fp16.h>
#include <cstdint>

// LSTMNet: embed(128->512) -> 3x LSTM(512) -> decode last step.
// B=256, T=256. f16 MFMA (16x16x32), fp32 accum, fp32 cell state.
//
// FINAL = R15 (best passing: 2944us). Temporal layer pipeline: 256 blocks
// (coop), g=blockIdx&7 (32 batch rows), hb=blockIdx>>3 (16 hidden units);
// per super-round r: L0 step r, L1 step r-1, L2 step r-2 (258 rounds, the
// per-round agent-RT chain amortized over 3 steps). All weights resident:
// W0,W1 as VGPR MFMA B-frags, W2 in 128KB LDS; Pl 32KB single-phase reduce
// (160KB LDS total). h via depth-16 rings, agent-scope relaxed atomics
// (sc0 sc1, MALL-coherent) - the ONLY cross-block memory path proven
// correct on this hardware (XCD-local sc0/L2 comm corrupted in R4/R6/R18,
// the last with spill-safe batched loads => hardware-refuted).
// Ceiling: 258 rounds x (~8.6us duplicated agent reads at the ~2.8TB/s
// latency*concurrency bound + ~2.5us own work) ~= 2.9ms. Flag restructure
// (R12/13/16), 8-wave (R14), data-polling (R7) all regressed; L2-dedup
// rings need >270MB ws (unavailable, R15).
// Guarded spins (no wedge); rule #20 respected; ld_cg16/st_cg2 spill-safe.

#define TT   256
#define NBAT 256
#define DIN  128
#define HID  512
#define RD   16

typedef _Float16 half_t;
typedef __attribute__((ext_vector_type(8))) _Float16 half8;
typedef __attribute__((ext_vector_type(4))) _Float16 half4v;
typedef __attribute__((ext_vector_type(4))) float f32x4;

__device__ __forceinline__ float sigmoidf_(float x) {
    return 1.f / (1.f + __expf(-x));
}
__device__ __forceinline__ float tanhf_(float x) {
    float xc = fminf(fmaxf(x, -15.f), 15.f);
    float e = __expf(2.f * xc);
    return (e - 1.f) / (e + 1.f);
}

// agent-scope (IF-coherent) 16B load; compiler-managed waits => spill-safe
__device__ __forceinline__ half8 ld_cg16(const half_t* p) {
    union { unsigned long long u[2]; half8 v; } r;
    r.u[0] = __hip_atomic_load((const unsigned long long*)p,
                               __ATOMIC_RELAXED, __HIP_MEMORY_SCOPE_AGENT);
    r.u[1] = __hip_atomic_load((const unsigned long long*)p + 1,
                               __ATOMIC_RELAXED, __HIP_MEMORY_SCOPE_AGENT);
    return r.v;
}
// agent-scope 2B store of one h value
__device__ __forceinline__ void st_cg2(half_t* p, float v) {
    half_t h = (half_t)v;
    unsigned short b = __builtin_bit_cast(unsigned short, h);
    __hip_atomic_store((unsigned short*)p, b,
                       __ATOMIC_RELAXED, __HIP_MEMORY_SCOPE_AGENT);
}

// write BOTH m-phases of partials into Pl[128][64] (XOR swizzle, 2-way free)
__device__ __forceinline__ void phase_out2(float* Pl, const f32x4 acc[2][4],
                                           int wv, int lane) {
    #pragma unroll
    for (int m = 0; m < 2; ++m)
        #pragma unroll
        for (int n = 0; n < 4; ++n)
            #pragma unroll
            for (int q = 0; q < 4; ++q) {
                int prow = (wv << 5) + (m << 4) + ((lane >> 4) << 2) + q;
                int cidx = (n << 4) + (lane & 15);
                Pl[prow * 64 + (cidx ^ ((((prow >> 2) ^ prow) & 1) << 4))] = acc[m][n][q];
            }
}
// reduce 4 K-chunk partials for batch-row `brow` + bias -> gates -> h
__device__ __forceinline__ float red_gatesS(const float* Pl, const float* b4,
                                            int brow, int jj, float& c) {
    float gs[4];
    #pragma unroll
    for (int gt = 0; gt < 4; ++gt) {
        float s = b4[gt];
        int cidx = (gt << 4) + jj;
        #pragma unroll
        for (int w2 = 0; w2 < 4; ++w2) {
            int r0 = (w2 << 5) + brow;
            s += Pl[r0 * 64 + (cidx ^ ((((r0 >> 2) ^ r0) & 1) << 4))];
        }
        gs[gt] = s;
    }
    float ig = sigmoidf_(gs[0]), fg = sigmoidf_(gs[1]);
    float gg = tanhf_(gs[2]), og = sigmoidf_(gs[3]);
    c = fg * c + ig * gg;
    return og * tanhf_(c);
}

// ---------------- weight conversion: fp32 w_ih|w_hh -> f16 MFMA-frag order
__global__ __launch_bounds__(256) void k_w16(const float* __restrict__ wih,
                                             const float* __restrict__ whh,
                                             half_t* __restrict__ wbuf) {
    half8* wb = (half8*)wbuf;
    const int bid = blockIdx.x;                // 0..383
    const int l = bid >> 7;
    const int rem = bid & 127;
    const int hb = rem >> 2, q = rem & 3;
    const int tid = threadIdx.x;
    #pragma unroll
    for (int i = 0; i < 8; ++i) {
        int unit = tid + (i << 8);             // 0..2047
        int kit = unit >> 8, n = (unit >> 6) & 3, lane = unit & 63;
        int grow = l * 2048 + n * 512 + hb * 16 + (lane & 15);
        int col = q * 256 + kit * 32 + ((lane >> 4) << 3);
        const float* src = (col < 512) ? (wih + (size_t)grow * HID + col)
                                       : (whh + (size_t)grow * HID + (col - 512));
        float4 u0 = *(const float4*)src;
        float4 u1 = *(const float4*)(src + 4);
        wb[((size_t)(l * 32 + hb) * 4 + q) * 2048 + unit] =
            (half8){(half_t)u0.x, (half_t)u0.y, (half_t)u0.z, (half_t)u0.w,
                    (half_t)u1.x, (half_t)u1.y, (half_t)u1.z, (half_t)u1.w};
    }
}

// ---------------- embed: out[t][b][j] = f16( x[b][t][:] . W[j][:] + bias[j] )
__global__ __launch_bounds__(256) void k_embed(const float* __restrict__ x,
                                               const float* __restrict__ W,
                                               const float* __restrict__ bias,
                                               half_t* __restrict__ out) {
    extern __shared__ char smem[];
    half_t* Xs = (half_t*)smem;            // [64][128] swizzled
    half_t* Ws = (half_t*)(smem + 16384);  // [512][128] swizzled
    const int tid = threadIdx.x;
    const int bk = blockIdx.x;
    const int t = bk >> 2, b0 = (bk & 3) << 6;

    #pragma unroll
    for (int it = 0; it < 8; ++it) {
        int idx = tid + (it << 8);
        int r = idx >> 5, k = (idx & 31) << 2;
        float4 v = *(const float4*)(x + ((size_t)(b0 + r) * TT + t) * DIN + k);
        half4v hv = {(half_t)v.x, (half_t)v.y, (half_t)v.z, (half_t)v.w};
        int byte = r * 256 + ((k * 2) ^ ((r & 7) << 4));
        *(half4v*)((char*)Xs + byte) = hv;
    }
    #pragma unroll 4
    for (int it = 0; it < 64; ++it) {
        int idx = tid + (it << 8);
        int r = idx >> 5, k = (idx & 31) << 2;
        float4 v = *(const float4*)(W + (size_t)r * DIN + k);
        half4v hv = {(half_t)v.x, (half_t)v.y, (half_t)v.z, (half_t)v.w};
        int byte = r * 256 + ((k * 2) ^ ((r & 7) << 4));
        *(half4v*)((char*)Ws + byte) = hv;
    }
    __syncthreads();

    const int lane = tid & 63, wv = tid >> 6;
    f32x4 acc[4][8];
    #pragma unroll
    for (int m = 0; m < 4; ++m)
        #pragma unroll
        for (int n = 0; n < 8; ++n) acc[m][n] = (f32x4){0.f, 0.f, 0.f, 0.f};

    #pragma unroll
    for (int kit = 0; kit < 4; ++kit) {
        int kk = (kit << 5) + ((lane >> 4) << 3);
        half8 a[4];
        #pragma unroll
        for (int m = 0; m < 4; ++m) {
            int r = (m << 4) + (lane & 15);
            int byte = r * 256 + ((kk * 2) ^ ((r & 7) << 4));
            a[m] = *(half8*)((char*)Xs + byte);
        }
        #pragma unroll
        for (int n = 0; n < 8; ++n) {
            int r = (wv << 7) + (n << 4) + (lane & 15);
            int byte = r * 256 + ((kk * 2) ^ ((r & 7) << 4));
            half8 b = *(half8*)((char*)Ws + byte);
            #pragma unroll
            for (int m = 0; m < 4; ++m)
                acc[m][n] = __builtin_amdgcn_mfma_f32_16x16x32_f16(a[m], b, acc[m][n], 0, 0, 0);
        }
    }
    __syncthreads();
    half_t* Os = (half_t*)smem;
    #pragma unroll
    for (int n = 0; n < 8; ++n) {
        int j = (wv << 7) + (n << 4) + (lane & 15);
        float bj = bias[j];
        #pragma unroll
        for (int m = 0; m < 4; ++m)
            #pragma unroll
            for (int r = 0; r < 4; ++r) {
                int mr = (m << 4) + ((lane >> 4) << 2) + r;
                Os[mr * 512 + j] = (half_t)(acc[m][n][r] + bj);
            }
    }
    __syncthreads();
    #pragma unroll
    for (int it = 0; it < 16; ++it) {
        int idx = tid + (it << 8);
        int r = idx >> 6, c = (idx & 63) << 3;
        half8 v = *(half8*)(Os + r * 512 + c);
        *(half8*)(out + ((size_t)t * NBAT + (b0 + r)) * HID + c) = v;
    }
}

// ---------------- persistent pipelined recurrent kernel
__global__ __launch_bounds__(256, 1) void k_rec(const half_t* __restrict__ wbuf,
                                                const half_t* __restrict__ bufE,
                                                half_t* __restrict__ ring0,
                                                half_t* __restrict__ ring1,
                                                half_t* __restrict__ ring2,
                                                half_t* __restrict__ outbuf,
                                                const float* __restrict__ b_ih,
                                                const float* __restrict__ b_hh,
                                                int* __restrict__ flags) {
    extern __shared__ char smem[];
    half8* W2s = (half8*)smem;                 // [4 q][8 kit][4 n][64] = 128KB
    float* Pl = (float*)(smem + 131072);       // [128][64] f32 = 32KB single-phase

    const half8* wb = (const half8*)wbuf;
    const int tid = threadIdx.x;
    const int lane = tid & 63, wv = tid >> 6;
    const int g = blockIdx.x & 7;
    const int hb = blockIdx.x >> 3;
    const int b0 = g << 5;
    const int j0 = hb << 4;
    const int rr = tid >> 4;                   // reduce row 0..15
    const int jj = tid & 15;
    const bool low = (wv < 2);                 // waves 0,1: E+h1; waves 2,3: h0+h2
    const int qw = wv ^ 2;                     // L1 K-quarter for this wave
    const int koff = ((wv & 1) << 8) + ((lane >> 4) << 3);
    bool dead = false;

    // ---- startup: W0,W1 -> VGPR; W2 -> LDS; biases
    half8 Bf0[8][4], Bf1[8][4];
    {
        const half8* w0 = wb + ((size_t)hb * 4 + wv) * 2048;
        const half8* w1 = wb + ((size_t)(32 + hb) * 4 + qw) * 2048;
        #pragma unroll
        for (int kit = 0; kit < 8; ++kit)
            #pragma unroll
            for (int n = 0; n < 4; ++n) {
                Bf0[kit][n] = w0[kit * 256 + n * 64 + lane];
                Bf1[kit][n] = w1[kit * 256 + n * 64 + lane];
            }
    }
    {
        const half8* w2 = wb + (size_t)(64 + hb) * 4 * 2048;
        #pragma unroll 4
        for (int it = 0; it < 32; ++it) {
            int idx = tid + (it << 8);
            W2s[idx] = w2[idx];
        }
    }
    float bias[3][4];
    #pragma unroll
    for (int l = 0; l < 3; ++l)
        #pragma unroll
        for (int gt = 0; gt < 4; ++gt)
            bias[l][gt] = b_ih[(size_t)l * 2048 + gt * HID + j0 + jj] +
                          b_hh[(size_t)l * 2048 + gt * HID + j0 + jj];
    float cA0 = 0.f, cA1 = 0.f, cB0 = 0.f, cB1 = 0.f, cC0 = 0.f, cC1 = 0.f;
    __syncthreads();

    const size_t RNG = (size_t)NBAT * HID;

    for (int r = 0; r < TT + 2; ++r) {
        const bool act0 = (r < TT);
        const bool act1 = (r >= 1 && r <= TT);
        const bool act2 = (r >= 2);

        // ---- top poll: flags[l] >= min(r-l, TT) (threads 0..95)
        if (tid < 96 && !dead) {
            int l = tid >> 5;
            int need = r - l; if (need > TT) need = TT;
            if (need > 0) {
                const int* fp = flags + l * 256 + (g << 5) + (tid & 31);
                int guard = 0;
                while (__hip_atomic_load(fp, __ATOMIC_RELAXED,
                                         __HIP_MEMORY_SCOPE_AGENT) < need) {
                    __builtin_amdgcn_s_sleep(1);
                    if (++guard > (1 << 17)) { dead = true; break; }
                }
            }
        }
        __syncthreads();

        // ---- p0: low = E(r) (plain cached), high = h0(r-1) (agent)
        half8 p0a[8], p0b[8];
        const size_t rowb = (size_t)(b0 + (lane & 15)) * HID + koff;
        if (low) {
            if (act0) {
                const half_t* ar = bufE + (size_t)r * RNG + rowb;
                #pragma unroll
                for (int kit = 0; kit < 8; ++kit) {
                    p0a[kit] = *(const half8*)(ar + (kit << 5));
                    p0b[kit] = *(const half8*)(ar + (size_t)16 * HID + (kit << 5));
                }
            }
        } else if (act1) {
            const half_t* ar = ring0 + (size_t)((r - 1) & (RD - 1)) * RNG + rowb;
            #pragma unroll
            for (int kit = 0; kit < 8; ++kit) {
                p0a[kit] = ld_cg16(ar + (kit << 5));
                p0b[kit] = ld_cg16(ar + (size_t)16 * HID + (kit << 5));
            }
        }

        f32x4 acc[2][4];

        // ================= layer 0 (step r): A = p0, B = Bf0 (VGPR) ==========
        #pragma unroll
        for (int m = 0; m < 2; ++m)
            #pragma unroll
            for (int n = 0; n < 4; ++n) acc[m][n] = (f32x4){0.f, 0.f, 0.f, 0.f};
        if (act0 && (low || r >= 1)) {
            #pragma unroll
            for (int kit = 0; kit < 8; ++kit)
                #pragma unroll
                for (int n = 0; n < 4; ++n) {
                    acc[0][n] = __builtin_amdgcn_mfma_f32_16x16x32_f16(p0a[kit], Bf0[kit][n], acc[0][n], 0, 0, 0);
                    acc[1][n] = __builtin_amdgcn_mfma_f32_16x16x32_f16(p0b[kit], Bf0[kit][n], acc[1][n], 0, 0, 0);
                }
        }
        // low: issue h1(r-2) now; hides under L0 reduce
        half8 p1a[8], p1b[8];
        if (low && r >= 2) {
            const half_t* ar = ring1 + (size_t)((r - 2) & (RD - 1)) * RNG + rowb;
            #pragma unroll
            for (int kit = 0; kit < 8; ++kit) {
                p1a[kit] = ld_cg16(ar + (kit << 5));
                p1b[kit] = ld_cg16(ar + (size_t)16 * HID + (kit << 5));
            }
        }
        {   // L0 single-phase reduce/gates/store -> ring0 slot r
            half_t* dst = ring0 + (size_t)(r & (RD - 1)) * RNG;
            phase_out2(Pl, acc, wv, lane);     // top-poll barrier protects Pl
            __syncthreads();
            if (act0) {
                st_cg2(dst + (size_t)(b0 + rr) * HID + j0 + jj,
                       red_gatesS(Pl, bias[0], rr, jj, cA0));
                st_cg2(dst + (size_t)(b0 + 16 + rr) * HID + j0 + jj,
                       red_gatesS(Pl, bias[0], 16 + rr, jj, cA1));
            }
            __syncthreads();
        }

        // ================= layer 1 (step r-1): low A=p1(h1), high A=p0(h0) ===
        #pragma unroll
        for (int m = 0; m < 2; ++m)
            #pragma unroll
            for (int n = 0; n < 4; ++n) acc[m][n] = (f32x4){0.f, 0.f, 0.f, 0.f};
        if (act1) {
            if (!low) {
                #pragma unroll
                for (int kit = 0; kit < 8; ++kit)
                    #pragma unroll
                    for (int n = 0; n < 4; ++n) {
                        acc[0][n] = __builtin_amdgcn_mfma_f32_16x16x32_f16(p0a[kit], Bf1[kit][n], acc[0][n], 0, 0, 0);
                        acc[1][n] = __builtin_amdgcn_mfma_f32_16x16x32_f16(p0b[kit], Bf1[kit][n], acc[1][n], 0, 0, 0);
                    }
            } else if (r >= 2) {
                #pragma unroll
                for (int kit = 0; kit < 8; ++kit)
                    #pragma unroll
                    for (int n = 0; n < 4; ++n) {
                        acc[0][n] = __builtin_amdgcn_mfma_f32_16x16x32_f16(p1a[kit], Bf1[kit][n], acc[0][n], 0, 0, 0);
                        acc[1][n] = __builtin_amdgcn_mfma_f32_16x16x32_f16(p1b[kit], Bf1[kit][n], acc[1][n], 0, 0, 0);
                    }
            }
        }
        // high: issue h2(r-3) now; hides under L1 reduce
        if (!low && r >= 3) {
            const half_t* ar = ring2 + (size_t)((r - 3) & (RD - 1)) * RNG + rowb;
            #pragma unroll
            for (int kit = 0; kit < 8; ++kit) {
                p1a[kit] = ld_cg16(ar + (kit << 5));
                p1b[kit] = ld_cg16(ar + (size_t)16 * HID + (kit << 5));
            }
        }
        {   // L1 single-phase -> ring1 slot r-1
            half_t* dst = ring1 + (size_t)((r - 1) & (RD - 1)) * RNG;
            phase_out2(Pl, acc, wv, lane);
            __syncthreads();
            if (act1) {
                st_cg2(dst + (size_t)(b0 + rr) * HID + j0 + jj,
                       red_gatesS(Pl, bias[1], rr, jj, cB0));
                st_cg2(dst + (size_t)(b0 + 16 + rr) * HID + j0 + jj,
                       red_gatesS(Pl, bias[1], 16 + rr, jj, cB1));
            }
            __syncthreads();
        }

        // ================= layer 2 (step r-2): A = p1, B = W2s (LDS) =========
        #pragma unroll
        for (int m = 0; m < 2; ++m)
            #pragma unroll
            for (int n = 0; n < 4; ++n) acc[m][n] = (f32x4){0.f, 0.f, 0.f, 0.f};
        if (act2 && (low || r >= 3)) {
            const half8* w2l = W2s + ((size_t)wv << 11);
            #pragma unroll
            for (int kit = 0; kit < 8; ++kit) {
                half8 B0 = w2l[kit * 256 + 0 * 64 + lane];
                half8 B1 = w2l[kit * 256 + 1 * 64 + lane];
                half8 B2 = w2l[kit * 256 + 2 * 64 + lane];
                half8 B3 = w2l[kit * 256 + 3 * 64 + lane];
                acc[0][0] = __builtin_amdgcn_mfma_f32_16x16x32_f16(p1a[kit], B0, acc[0][0], 0, 0, 0);
                acc[1][0] = __builtin_amdgcn_mfma_f32_16x16x32_f16(p1b[kit], B0, acc[1][0], 0, 0, 0);
                acc[0][1] = __builtin_amdgcn_mfma_f32_16x16x32_f16(p1a[kit], B1, acc[0][1], 0, 0, 0);
                acc[1][1] = __builtin_amdgcn_mfma_f32_16x16x32_f16(p1b[kit], B1, acc[1][1], 0, 0, 0);
                acc[0][2] = __builtin_amdgcn_mfma_f32_16x16x32_f16(p1a[kit], B2, acc[0][2], 0, 0, 0);
                acc[1][2] = __builtin_amdgcn_mfma_f32_16x16x32_f16(p1b[kit], B2, acc[1][2], 0, 0, 0);
                acc[0][3] = __builtin_amdgcn_mfma_f32_16x16x32_f16(p1a[kit], B3, acc[0][3], 0, 0, 0);
                acc[1][3] = __builtin_amdgcn_mfma_f32_16x16x32_f16(p1b[kit], B3, acc[1][3], 0, 0, 0);
            }
        }
        {   // L2 single-phase -> ring2 slot r-2 (+ outbuf at final step)
            const int t2 = r - 2;
            half_t* dst = ring2 + (size_t)(t2 & (RD - 1)) * RNG;
            phase_out2(Pl, acc, wv, lane);
            __syncthreads();
            if (act2) {
                float h0v = red_gatesS(Pl, bias[2], rr, jj, cC0);
                float h1v = red_gatesS(Pl, bias[2], 16 + rr, jj, cC1);
                st_cg2(dst + (size_t)(b0 + rr) * HID + j0 + jj, h0v);
                st_cg2(dst + (size_t)(b0 + 16 + rr) * HID + j0 + jj, h1v);
                if (t2 == TT - 1) {
                    st_cg2(outbuf + (size_t)(b0 + rr) * HID + j0 + jj, h0v);
                    st_cg2(outbuf + (size_t)(b0 + 16 + rr) * HID + j0 + jj, h1v);
                }
            }
        }

        // ---- release: one drain, barrier, publish all 3 flags
        asm volatile("s_waitcnt vmcnt(0)" ::: "memory");
        __builtin_amdgcn_sched_barrier(0);
        __syncthreads();
        if (tid == 0 && act0)
            __hip_atomic_store(flags + 0 * 256 + (g << 5) + hb, r + 1,
                               __ATOMIC_RELAXED, __HIP_MEMORY_SCOPE_AGENT);
        if (tid == 1 && act1)
            __hip_atomic_store(flags + 1 * 256 + (g << 5) + hb, r,
                               __ATOMIC_RELAXED, __HIP_MEMORY_SCOPE_AGENT);
        if (tid == 2 && act2)
            __hip_atomic_store(flags + 2 * 256 + (g << 5) + hb, r - 1,
                               __ATOMIC_RELAXED, __HIP_MEMORY_SCOPE_AGENT);
    }
}

// ---------------- decoder: out[b] = h2[T-1][b][:] . dec_W + dec_b
__global__ __launch_bounds__(256) void k_dec(const half_t* __restrict__ act,
                                             const float* __restrict__ dW,
                                             const float* __restrict__ db,
                                             float* __restrict__ out) {
    int tid = threadIdx.x;
    int bl = tid >> 3, part = tid & 7;
    int b = (blockIdx.x << 5) + bl;
    const half_t* row = act + (size_t)b * HID + (part << 6);
    float s = 0.f;
    #pragma unroll
    for (int i = 0; i < 8; ++i) {
        half8 v = ld_cg16(row + (i << 3));
        const float* wp = dW + (part << 6) + (i << 3);
        #pragma unroll
        for (int u = 0; u < 8; ++u) s += (float)v[u] * wp[u];
    }
    #pragma unroll
    for (int off = 1; off < 8; off <<= 1) s += __shfl_xor(s, off, 64);
    if (part == 0) out[b] = s + db[0];
}

extern "C" void kernel_launch(void* const* d_in, const int* in_sizes, int n_in,
                              void* d_out, int out_size, void* d_ws, size_t ws_size,
                              hipStream_t stream) {
    const float* x = (const float*)d_in[0];
    const float* eW = (const float*)d_in[1];
    const float* eb = (const float*)d_in[2];
    const float* wih = (const float*)d_in[3];
    const float* whh = (const float*)d_in[4];
    const float* bih = (const float*)d_in[5];
    const float* bhh = (const float*)d_in[6];
    const float* dW = (const float*)d_in[7];
    const float* db = (const float*)d_in[8];
    float* out = (float*)d_out;

    const size_t MB = 1u << 20;
    if (ws_size < 96 * MB + 65536) return;        // insufficient workspace

    char* ws = (char*)d_ws;
    half_t* bufE = (half_t*)ws;                   // 64 MB
    half_t* ring0 = (half_t*)(ws + 64 * MB);      // 4 MB each (depth 16)
    half_t* ring1 = (half_t*)(ws + 68 * MB);
    half_t* ring2 = (half_t*)(ws + 72 * MB);
    half_t* outbuf = (half_t*)(ws + 76 * MB);
    half_t* wbuf = (half_t*)(ws + 80 * MB);
    int* flags = (int*)(ws + 96 * MB);            // 768 flags

    hipMemsetAsync(flags, 0, 1024 * sizeof(int), stream);

    (void)hipFuncSetAttribute((const void*)k_embed,
                              hipFuncAttributeMaxDynamicSharedMemorySize, 147456);
    (void)hipFuncSetAttribute((const void*)k_rec,
                              hipFuncAttributeMaxDynamicSharedMemorySize, 163840);

    k_w16<<<384, 256, 0, stream>>>(wih, whh, wbuf);
    k_embed<<<1024, 256, 147456, stream>>>(x, eW, eb, bufE);

    void* args[] = { (void*)&wbuf, (void*)&bufE, (void*)&ring0, (void*)&ring1,
                     (void*)&ring2, (void*)&outbuf, (void*)&bih, (void*)&bhh,
                     (void*)&flags };
    hipError_t ce = hipLaunchCooperativeKernel((const void*)k_rec, dim3(256), dim3(256),
                                               args, 163840, stream);
    if (ce != hipSuccess) {
        k_rec<<<256, 256, 163840, stream>>>(wbuf, bufE, ring0, ring1, ring2,
                                            outbuf, bih, bhh, flags);
    }

    k_dec<<<8, 256, 0, stream>>>(outbuf, dW, db, out);
}